// Round 1
// 1296.340 us; speedup vs baseline: 1.7731x; 1.7731x over previous
//
#include <hip/hip_runtime.h>
#include <hip/hip_fp16.h>
#include <cstdint>
#include <cstddef>

// Problem constants (fixed by reference)
#define CB    4096          // codebook size C
#define DD    512           // dim D (= K of the GEMM)
#define M_TOK 32768         // B*N tokens
#define DECAY_F 0.8f
#define OMD_F   0.2f        // 1 - DECAY
#define EPS_F   1e-5f

// Output layout (flat float32, reference return order)
#define OFF_QUANT ((size_t)0)
#define SZ_QUANT  ((size_t)M_TOK * DD)            // 16777216
#define OFF_IND   (OFF_QUANT + SZ_QUANT)
#define SZ_IND    ((size_t)M_TOK)                 // 32768
#define OFF_DIST  (OFF_IND + SZ_IND)
#define SZ_DIST   ((size_t)M_TOK * CB)            // 134217728
#define OFF_NC    (OFF_DIST + SZ_DIST)
#define SZ_NC     ((size_t)CB)
#define OFF_AVG   (OFF_NC + SZ_NC)
#define SZ_AVG    ((size_t)CB * DD)
#define OFF_NEMB  (OFF_AVG + SZ_AVG)

typedef unsigned short ushort_b;
typedef __attribute__((ext_vector_type(8))) short f16x8;   // 8 fp16 = 4 VGPRs (MFMA A/B frag)
typedef __attribute__((ext_vector_type(4))) float f32x4;   // MFMA C/D frag

// ---------------------------------------------------------------- K0: init
// avg_out = 0.8 * embed_avg ; zero bins ; zero tot
__global__ __launch_bounds__(256) void k_init(const float* __restrict__ eavg,
                                              float* __restrict__ avg_out,
                                              int* __restrict__ bins,
                                              float* __restrict__ tot) {
  size_t id = (size_t)blockIdx.x * 256 + threadIdx.x;   // 0..524287 (float4 units)
  float4 v = *(const float4*)(eavg + id * 4);
  float4 o;
  o.x = v.x * DECAY_F; o.y = v.y * DECAY_F; o.z = v.z * DECAY_F; o.w = v.w * DECAY_F;
  *(float4*)(avg_out + id * 4) = o;
  if (id < CB) bins[id] = 0;
  if (id == CB) *tot = 0.0f;
}

// ---------------------------------------------------------------- K0b: fp32 -> fp16 hi/lo split
// hi = f16(x), lo = f16(x - hi). hi+lo carries ~22 mantissa bits.
__global__ __launch_bounds__(256) void k_split(const float* __restrict__ src,
                                               ushort_b* __restrict__ hi,
                                               ushort_b* __restrict__ lo) {
  size_t id = (size_t)blockIdx.x * 256 + threadIdx.x;   // units of 8 floats
  const float* p = src + id * 8;
  float4 v0 = *(const float4*)p;
  float4 v1 = *(const float4*)(p + 4);
  float f[8] = {v0.x, v0.y, v0.z, v0.w, v1.x, v1.y, v1.z, v1.w};
  ushort_b h[8], l[8];
#pragma unroll
  for (int j = 0; j < 8; ++j) {
    __half hh = __float2half(f[j]);                      // RNE
    h[j] = __half_as_ushort(hh);
    float r = f[j] - __half2float(hh);                   // exact in fp32
    l[j] = __half_as_ushort(__float2half(r));
  }
  uint4 H, L;
  H.x = h[0] | ((unsigned)h[1] << 16); H.y = h[2] | ((unsigned)h[3] << 16);
  H.z = h[4] | ((unsigned)h[5] << 16); H.w = h[6] | ((unsigned)h[7] << 16);
  L.x = l[0] | ((unsigned)l[1] << 16); L.y = l[2] | ((unsigned)l[3] << 16);
  L.z = l[4] | ((unsigned)l[5] << 16); L.w = l[6] | ((unsigned)l[7] << 16);
  *(uint4*)(hi + id * 8) = H;
  *(uint4*)(lo + id * 8) = L;
}

// ---------------------------------------------------------------- K1: MFMA split-GEMM
// dist[m][c] = sum_k X[m][k]*E[c][k] via (Xh+Xl)·(Eh+El) dropping Xl·El.
// 128x128 tile, BK=32, 4 waves, 4x4 frags of mfma_f32_16x16x32_f16 each, 3 passes.
#define TSZ 4096   // ushorts per LDS tile (128 rows x 32 f16)

__device__ __forceinline__ void gload16(const void* g, void* l) {
  __builtin_amdgcn_global_load_lds((const __attribute__((address_space(1))) unsigned int*)g,
                                   (__attribute__((address_space(3))) unsigned int*)l,
                                   16, 0, 0);
}

__global__ __launch_bounds__(256) void k_dist_mfma(const ushort_b* __restrict__ Xhi,
                                                   const ushort_b* __restrict__ Xlo,
                                                   const ushort_b* __restrict__ Ehi,
                                                   const ushort_b* __restrict__ Elo,
                                                   float* __restrict__ dist) {
  // tiles: [0]=Ahi [1]=Alo [2]=Bhi [3]=Blo ; layout [row][slot] 16B chunks,
  // chunk at slot s holds global k-chunk q = s ^ ((row>>1)&3)  (XOR swizzle,
  // applied identically on the pre-swizzled global source and on ds_read)
  __shared__ __align__(16) ushort_b lds[4 * TSZ];
  const int tid  = threadIdx.x;
  const int lane = tid & 63;
  const int wid  = tid >> 6;          // 0..3
  const int wr   = wid >> 1;          // wave row (0/1) -> 64 rows
  const int wc   = wid & 1;           // wave col (0/1) -> 64 cols
  const int bn   = blockIdx.x;        // 0..31
  const int bm   = blockIdx.y;        // 0..255

  const size_t abase = (size_t)bm * 128 * DD;
  const size_t bbase = (size_t)bn * 128 * DD;

  // staging: 512 16B-chunks per tile, 2 per thread (l=0,1)
  const int chunk0 = tid;
  const int chunk1 = tid + 256;
  const int row0 = chunk0 >> 2, slot0 = chunk0 & 3;
  const int row1 = chunk1 >> 2, slot1 = chunk1 & 3;
  const int q0 = slot0 ^ ((row0 >> 1) & 3);
  const int q1 = slot1 ^ ((row1 >> 1) & 3);
  const size_t g0 = (size_t)row0 * DD + q0 * 8;   // element offset (+ kt later)
  const size_t g1 = (size_t)row1 * DD + q1 * 8;
  // wave-uniform LDS bases (ushort units); HW adds lane*16B
  const int lb0 = (wid * 64) * 8;
  const int lb1 = (wid * 64 + 256) * 8;

  f32x4 acc[4][4];
#pragma unroll
  for (int i = 0; i < 4; ++i)
#pragma unroll
    for (int j = 0; j < 4; ++j) acc[i][j] = (f32x4){0.f, 0.f, 0.f, 0.f};

  // fragment read offsets (ushort units), swizzle-matched
  const int qr = lane >> 4;           // k-chunk this quarter-wave reads
  int aoff[4], boff[4];
#pragma unroll
  for (int mi = 0; mi < 4; ++mi) {
    int row = wr * 64 + mi * 16 + (lane & 15);
    aoff[mi] = row * 32 + ((qr ^ ((row >> 1) & 3)) << 3);
  }
#pragma unroll
  for (int ni = 0; ni < 4; ++ni) {
    int col = wc * 64 + ni * 16 + (lane & 15);
    boff[ni] = col * 32 + ((qr ^ ((col >> 1) & 3)) << 3);
  }

  for (int kt = 0; kt < DD; kt += 32) {
    gload16(Xhi + abase + g0 + kt, &lds[0 * TSZ + lb0]);
    gload16(Xhi + abase + g1 + kt, &lds[0 * TSZ + lb1]);
    gload16(Xlo + abase + g0 + kt, &lds[1 * TSZ + lb0]);
    gload16(Xlo + abase + g1 + kt, &lds[1 * TSZ + lb1]);
    gload16(Ehi + bbase + g0 + kt, &lds[2 * TSZ + lb0]);
    gload16(Ehi + bbase + g1 + kt, &lds[2 * TSZ + lb1]);
    gload16(Elo + bbase + g0 + kt, &lds[3 * TSZ + lb0]);
    gload16(Elo + bbase + g1 + kt, &lds[3 * TSZ + lb1]);
    __syncthreads();

    f16x8 ah[4], al[4], bh[4], bl[4];
#pragma unroll
    for (int mi = 0; mi < 4; ++mi) {
      ah[mi] = *(const f16x8*)&lds[0 * TSZ + aoff[mi]];
      al[mi] = *(const f16x8*)&lds[1 * TSZ + aoff[mi]];
    }
#pragma unroll
    for (int ni = 0; ni < 4; ++ni) {
      bh[ni] = *(const f16x8*)&lds[2 * TSZ + boff[ni]];
      bl[ni] = *(const f16x8*)&lds[3 * TSZ + boff[ni]];
    }
#pragma unroll
    for (int mi = 0; mi < 4; ++mi)
#pragma unroll
      for (int ni = 0; ni < 4; ++ni) {
        acc[mi][ni] = __builtin_amdgcn_mfma_f32_16x16x32_f16(ah[mi], bh[ni], acc[mi][ni], 0, 0, 0);
        acc[mi][ni] = __builtin_amdgcn_mfma_f32_16x16x32_f16(al[mi], bh[ni], acc[mi][ni], 0, 0, 0);
        acc[mi][ni] = __builtin_amdgcn_mfma_f32_16x16x32_f16(ah[mi], bl[ni], acc[mi][ni], 0, 0, 0);
      }
    __syncthreads();
  }

  // epilogue: D row = (lane>>4)*4 + reg, col = lane&15  (m89-verified layout)
  const int rbase = bm * 128 + wr * 64 + (lane >> 4) * 4;
  const int cbase = bn * 128 + wc * 64 + (lane & 15);
#pragma unroll
  for (int mi = 0; mi < 4; ++mi)
#pragma unroll
    for (int r = 0; r < 4; ++r) {
      float* drow = dist + (size_t)(rbase + mi * 16 + r) * CB + cbase;
#pragma unroll
      for (int ni = 0; ni < 4; ++ni) drow[ni * 16] = acc[mi][ni][r];
    }
}

// ---------------------------------------------------------------- K2: argmax rows (+histogram)
__global__ __launch_bounds__(256) void k_argmax(const float* __restrict__ dist,
                                                float* __restrict__ ind_f,
                                                int* __restrict__ idx_ws,
                                                int* __restrict__ bins) {
  const int row = blockIdx.x;
  const float* p = dist + (size_t)row * CB;
  const int tid = threadIdx.x;
  float best = -3.402823466e38f;
  int bi = 0;
#pragma unroll
  for (int it = 0; it < 4; ++it) {
    int j4 = (tid + it * 256) << 2;      // ascending within thread -> strict > keeps first
    float4 v = *(const float4*)(p + j4);
    if (v.x > best) { best = v.x; bi = j4; }
    if (v.y > best) { best = v.y; bi = j4 + 1; }
    if (v.z > best) { best = v.z; bi = j4 + 2; }
    if (v.w > best) { best = v.w; bi = j4 + 3; }
  }
  // wave reduce (64 lanes), first-occurrence tie-break
  for (int off = 32; off; off >>= 1) {
    float ov = __shfl_down(best, off);
    int   oi = __shfl_down(bi, off);
    if (ov > best || (ov == best && oi < bi)) { best = ov; bi = oi; }
  }
  __shared__ float sv[4];
  __shared__ int   si[4];
  int wid = tid >> 6;
  if ((tid & 63) == 0) { sv[wid] = best; si[wid] = bi; }
  __syncthreads();
  if (tid == 0) {
#pragma unroll
    for (int w = 1; w < 4; ++w)
      if (sv[w] > best || (sv[w] == best && si[w] < bi)) { best = sv[w]; bi = si[w]; }
    ind_f[row]  = (float)bi;
    idx_ws[row] = bi;
    atomicAdd(&bins[bi], 1);
  }
}

// ---------------------------------------------------------------- K3: quantize gather + embed_sum scatter
__global__ __launch_bounds__(256) void k_quant_scatter(const float* __restrict__ X,
                                                       const float* __restrict__ E,
                                                       const int* __restrict__ idx_ws,
                                                       float* __restrict__ quant,
                                                       float* __restrict__ avg) {
  size_t id = (size_t)blockIdx.x * 256 + threadIdx.x;   // 0..4194303 (float4 units)
  int n  = (int)(id >> 7);
  int d4 = (int)(id & 127) << 2;
  int c  = idx_ws[n];
  float4 e = *(const float4*)(E + (size_t)c * DD + d4);
  *(float4*)(quant + (size_t)n * DD + d4) = e;
  float4 xv = *(const float4*)(X + (size_t)n * DD + d4);
  float* dst = avg + (size_t)c * DD + d4;
  atomicAdd(dst + 0, OMD_F * xv.x);
  atomicAdd(dst + 1, OMD_F * xv.y);
  atomicAdd(dst + 2, OMD_F * xv.z);
  atomicAdd(dst + 3, OMD_F * xv.w);
}

// ---------------------------------------------------------------- K4: new_cluster + total
__global__ __launch_bounds__(256) void k_cluster(const float* __restrict__ cs,
                                                 const int* __restrict__ bins,
                                                 float* __restrict__ nc_out,
                                                 float* __restrict__ tot) {
  int c = blockIdx.x * 256 + threadIdx.x;   // grid 16 -> 4096
  float nc = DECAY_F * cs[c] + OMD_F * (float)bins[c];
  nc_out[c] = nc;
  float s = nc;
  for (int off = 32; off; off >>= 1) s += __shfl_down(s, off);
  if ((threadIdx.x & 63) == 0) atomicAdd(tot, s);
}

// ---------------------------------------------------------------- K5: laplace-smooth + l2norm rows
__global__ __launch_bounds__(128) void k_norm(const float* __restrict__ avg,
                                              const float* __restrict__ nc,
                                              const float* __restrict__ tot,
                                              float* __restrict__ out) {
  int c = blockIdx.x;
  int tid = threadIdx.x;                     // 128 threads, D=512 -> float4 each
  const float* row = avg + (size_t)c * DD;
  float4 v = *(const float4*)(row + tid * 4);
  float ss = v.x * v.x + v.y * v.y + v.z * v.z + v.w * v.w;
  for (int off = 32; off; off >>= 1) ss += __shfl_down(ss, off);
  __shared__ float s2[2];
  if ((tid & 63) == 0) s2[tid >> 6] = ss;
  __syncthreads();
  float sumsq = s2[0] + s2[1];
  float t = *tot;
  float sm = (nc[c] + EPS_F) / (t + (float)CB * EPS_F) * t;   // > 0
  float nrm = sqrtf(sumsq) / sm;             // ||avg/sm||
  float denom = fmaxf(nrm, 1e-12f);
  float scale = 1.0f / (sm * denom);
  float4 o;
  o.x = v.x * scale; o.y = v.y * scale; o.z = v.z * scale; o.w = v.w * scale;
  *(float4*)(out + (size_t)c * DD + tid * 4) = o;
}

// ---------------------------------------------------------------- launch
extern "C" void kernel_launch(void* const* d_in, const int* in_sizes, int n_in,
                              void* d_out, int out_size, void* d_ws, size_t ws_size,
                              hipStream_t stream) {
  const float* x     = (const float*)d_in[0];   // (8,4096,512)
  const float* embed = (const float*)d_in[1];   // (1,4096,512)
  const float* cs    = (const float*)d_in[2];   // (1,4096)
  const float* eavg  = (const float*)d_in[3];   // (1,4096,512)

  float* out    = (float*)d_out;
  float* quant  = out + OFF_QUANT;
  float* indf   = out + OFF_IND;
  float* dist   = out + OFF_DIST;
  float* ncout  = out + OFF_NC;
  float* avgout = out + OFF_AVG;
  float* nemb   = out + OFF_NEMB;

  int*   idx_ws = (int*)d_ws;                 // 32768 ints
  int*   bins   = idx_ws + M_TOK;             // 4096 ints
  float* tot    = (float*)(bins + CB);        // 1 float

  // fp16 hi/lo scratch aliased onto not-yet-written output regions:
  //   X hi+lo (67.1 MB) -> quant region (written later by k_quant_scatter)
  //   E hi+lo ( 8.4 MB) -> nemb region  (written last by k_norm)
  ushort_b* xhi = (ushort_b*)quant;
  ushort_b* xlo = xhi + (size_t)M_TOK * DD;
  ushort_b* ehi = (ushort_b*)nemb;
  ushort_b* elo = ehi + (size_t)CB * DD;

  k_init<<<dim3(2048), dim3(256), 0, stream>>>(eavg, avgout, bins, tot);
  k_split<<<dim3(M_TOK * DD / 8 / 256), dim3(256), 0, stream>>>(x, xhi, xlo);
  k_split<<<dim3(CB * DD / 8 / 256), dim3(256), 0, stream>>>(embed, ehi, elo);
  k_dist_mfma<<<dim3(CB / 128, M_TOK / 128), dim3(256), 0, stream>>>(xhi, xlo, ehi, elo, dist);
  k_argmax<<<dim3(M_TOK), dim3(256), 0, stream>>>(dist, indf, idx_ws, bins);
  k_quant_scatter<<<dim3(16384), dim3(256), 0, stream>>>(x, embed, idx_ws, quant, avgout);
  k_cluster<<<dim3(16), dim3(256), 0, stream>>>(cs, bins, ncout, tot);
  k_norm<<<dim3(CB), dim3(128), 0, stream>>>(avgout, ncout, tot, nemb);
}

// Round 2
// 1110.756 us; speedup vs baseline: 2.0693x; 1.1671x over previous
//
#include <hip/hip_runtime.h>
#include <hip/hip_fp16.h>
#include <cstdint>
#include <cstddef>

// Problem constants (fixed by reference)
#define CB    4096          // codebook size C
#define DD    512           // dim D (= K of the GEMM)
#define M_TOK 32768         // B*N tokens
#define DECAY_F 0.8f
#define OMD_F   0.2f        // 1 - DECAY
#define EPS_F   1e-5f

// Output layout (flat float32, reference return order)
#define OFF_QUANT ((size_t)0)
#define SZ_QUANT  ((size_t)M_TOK * DD)            // 16777216
#define OFF_IND   (OFF_QUANT + SZ_QUANT)
#define SZ_IND    ((size_t)M_TOK)                 // 32768
#define OFF_DIST  (OFF_IND + SZ_IND)
#define SZ_DIST   ((size_t)M_TOK * CB)            // 134217728
#define OFF_NC    (OFF_DIST + SZ_DIST)
#define SZ_NC     ((size_t)CB)
#define OFF_AVG   (OFF_NC + SZ_NC)
#define SZ_AVG    ((size_t)CB * DD)
#define OFF_NEMB  (OFF_AVG + SZ_AVG)

typedef unsigned short ushort_b;
typedef __attribute__((ext_vector_type(8))) short f16x8;   // 8 fp16 = 4 VGPRs (MFMA A/B frag)
typedef __attribute__((ext_vector_type(4))) float f32x4;   // MFMA C/D frag

// ---------------------------------------------------------------- K0: init bins/tot
__global__ __launch_bounds__(256) void k_init(int* __restrict__ bins,
                                              float* __restrict__ tot) {
  int id = blockIdx.x * 256 + threadIdx.x;
  if (id < CB) bins[id] = 0;
  if (id == 0) *tot = 0.0f;
}

// ---------------------------------------------------------------- K0b: fp32 -> fp16 hi/lo split
// hi = f16(x), lo = f16(x - hi). hi+lo carries ~22 mantissa bits.
__global__ __launch_bounds__(256) void k_split(const float* __restrict__ src,
                                               ushort_b* __restrict__ hi,
                                               ushort_b* __restrict__ lo) {
  size_t id = (size_t)blockIdx.x * 256 + threadIdx.x;   // units of 8 floats
  const float* p = src + id * 8;
  float4 v0 = *(const float4*)p;
  float4 v1 = *(const float4*)(p + 4);
  float f[8] = {v0.x, v0.y, v0.z, v0.w, v1.x, v1.y, v1.z, v1.w};
  ushort_b h[8], l[8];
#pragma unroll
  for (int j = 0; j < 8; ++j) {
    __half hh = __float2half(f[j]);                      // RNE
    h[j] = __half_as_ushort(hh);
    float r = f[j] - __half2float(hh);                   // exact in fp32
    l[j] = __half_as_ushort(__float2half(r));
  }
  uint4 H, L;
  H.x = h[0] | ((unsigned)h[1] << 16); H.y = h[2] | ((unsigned)h[3] << 16);
  H.z = h[4] | ((unsigned)h[5] << 16); H.w = h[6] | ((unsigned)h[7] << 16);
  L.x = l[0] | ((unsigned)l[1] << 16); L.y = l[2] | ((unsigned)l[3] << 16);
  L.z = l[4] | ((unsigned)l[5] << 16); L.w = l[6] | ((unsigned)l[7] << 16);
  *(uint4*)(hi + id * 8) = H;
  *(uint4*)(lo + id * 8) = L;
}

// ---------------------------------------------------------------- K1: MFMA split-GEMM
// dist[m][c] = sum_k X[m][k]*E[c][k] via (Xh+Xl)·(Eh+El) dropping Xl·El.
// 128x128 tile, BK=32, 4 waves, 4x4 frags of mfma_f32_16x16x32_f16 each, 3 passes.
#define TSZ 4096   // ushorts per LDS tile (128 rows x 32 f16)

__device__ __forceinline__ void gload16(const void* g, void* l) {
  __builtin_amdgcn_global_load_lds((const __attribute__((address_space(1))) unsigned int*)g,
                                   (__attribute__((address_space(3))) unsigned int*)l,
                                   16, 0, 0);
}

__global__ __launch_bounds__(256) void k_dist_mfma(const ushort_b* __restrict__ Xhi,
                                                   const ushort_b* __restrict__ Xlo,
                                                   const ushort_b* __restrict__ Ehi,
                                                   const ushort_b* __restrict__ Elo,
                                                   float* __restrict__ dist) {
  // tiles: [0]=Ahi [1]=Alo [2]=Bhi [3]=Blo ; layout [row][slot] 16B chunks,
  // chunk at slot s holds global k-chunk q = s ^ ((row>>1)&3)  (XOR swizzle,
  // applied identically on the pre-swizzled global source and on ds_read)
  __shared__ __align__(16) ushort_b lds[4 * TSZ];
  const int tid  = threadIdx.x;
  const int lane = tid & 63;
  const int wid  = tid >> 6;          // 0..3
  const int wr   = wid >> 1;          // wave row (0/1) -> 64 rows
  const int wc   = wid & 1;           // wave col (0/1) -> 64 cols
  const int bn   = blockIdx.x;        // 0..31
  const int bm   = blockIdx.y;        // 0..255

  const size_t abase = (size_t)bm * 128 * DD;
  const size_t bbase = (size_t)bn * 128 * DD;

  // staging: 512 16B-chunks per tile, 2 per thread (l=0,1)
  const int chunk0 = tid;
  const int chunk1 = tid + 256;
  const int row0 = chunk0 >> 2, slot0 = chunk0 & 3;
  const int row1 = chunk1 >> 2, slot1 = chunk1 & 3;
  const int q0 = slot0 ^ ((row0 >> 1) & 3);
  const int q1 = slot1 ^ ((row1 >> 1) & 3);
  const size_t g0 = (size_t)row0 * DD + q0 * 8;   // element offset (+ kt later)
  const size_t g1 = (size_t)row1 * DD + q1 * 8;
  // wave-uniform LDS bases (ushort units); HW adds lane*16B
  const int lb0 = (wid * 64) * 8;
  const int lb1 = (wid * 64 + 256) * 8;

  f32x4 acc[4][4];
#pragma unroll
  for (int i = 0; i < 4; ++i)
#pragma unroll
    for (int j = 0; j < 4; ++j) acc[i][j] = (f32x4){0.f, 0.f, 0.f, 0.f};

  // fragment read offsets (ushort units), swizzle-matched
  const int qr = lane >> 4;           // k-chunk this quarter-wave reads
  int aoff[4], boff[4];
#pragma unroll
  for (int mi = 0; mi < 4; ++mi) {
    int row = wr * 64 + mi * 16 + (lane & 15);
    aoff[mi] = row * 32 + ((qr ^ ((row >> 1) & 3)) << 3);
  }
#pragma unroll
  for (int ni = 0; ni < 4; ++ni) {
    int col = wc * 64 + ni * 16 + (lane & 15);
    boff[ni] = col * 32 + ((qr ^ ((col >> 1) & 3)) << 3);
  }

  for (int kt = 0; kt < DD; kt += 32) {
    gload16(Xhi + abase + g0 + kt, &lds[0 * TSZ + lb0]);
    gload16(Xhi + abase + g1 + kt, &lds[0 * TSZ + lb1]);
    gload16(Xlo + abase + g0 + kt, &lds[1 * TSZ + lb0]);
    gload16(Xlo + abase + g1 + kt, &lds[1 * TSZ + lb1]);
    gload16(Ehi + bbase + g0 + kt, &lds[2 * TSZ + lb0]);
    gload16(Ehi + bbase + g1 + kt, &lds[2 * TSZ + lb1]);
    gload16(Elo + bbase + g0 + kt, &lds[3 * TSZ + lb0]);
    gload16(Elo + bbase + g1 + kt, &lds[3 * TSZ + lb1]);
    __syncthreads();

    f16x8 ah[4], al[4], bh[4], bl[4];
#pragma unroll
    for (int mi = 0; mi < 4; ++mi) {
      ah[mi] = *(const f16x8*)&lds[0 * TSZ + aoff[mi]];
      al[mi] = *(const f16x8*)&lds[1 * TSZ + aoff[mi]];
    }
#pragma unroll
    for (int ni = 0; ni < 4; ++ni) {
      bh[ni] = *(const f16x8*)&lds[2 * TSZ + boff[ni]];
      bl[ni] = *(const f16x8*)&lds[3 * TSZ + boff[ni]];
    }
#pragma unroll
    for (int mi = 0; mi < 4; ++mi)
#pragma unroll
      for (int ni = 0; ni < 4; ++ni) {
        acc[mi][ni] = __builtin_amdgcn_mfma_f32_16x16x32_f16(ah[mi], bh[ni], acc[mi][ni], 0, 0, 0);
        acc[mi][ni] = __builtin_amdgcn_mfma_f32_16x16x32_f16(al[mi], bh[ni], acc[mi][ni], 0, 0, 0);
        acc[mi][ni] = __builtin_amdgcn_mfma_f32_16x16x32_f16(ah[mi], bl[ni], acc[mi][ni], 0, 0, 0);
      }
    __syncthreads();
  }

  // epilogue: D row = (lane>>4)*4 + reg, col = lane&15  (m89-verified layout)
  const int rbase = bm * 128 + wr * 64 + (lane >> 4) * 4;
  const int cbase = bn * 128 + wc * 64 + (lane & 15);
#pragma unroll
  for (int mi = 0; mi < 4; ++mi)
#pragma unroll
    for (int r = 0; r < 4; ++r) {
      float* drow = dist + (size_t)(rbase + mi * 16 + r) * CB + cbase;
#pragma unroll
      for (int ni = 0; ni < 4; ++ni) drow[ni * 16] = acc[mi][ni][r];
    }
}

// ---------------------------------------------------------------- K2: argmax rows (+histogram)
__global__ __launch_bounds__(256) void k_argmax(const float* __restrict__ dist,
                                                float* __restrict__ ind_f,
                                                int* __restrict__ idx_ws,
                                                int* __restrict__ bins) {
  const int row = blockIdx.x;
  const float* p = dist + (size_t)row * CB;
  const int tid = threadIdx.x;
  float best = -3.402823466e38f;
  int bi = 0;
#pragma unroll
  for (int it = 0; it < 4; ++it) {
    int j4 = (tid + it * 256) << 2;      // ascending within thread -> strict > keeps first
    float4 v = *(const float4*)(p + j4);
    if (v.x > best) { best = v.x; bi = j4; }
    if (v.y > best) { best = v.y; bi = j4 + 1; }
    if (v.z > best) { best = v.z; bi = j4 + 2; }
    if (v.w > best) { best = v.w; bi = j4 + 3; }
  }
  // wave reduce (64 lanes), first-occurrence tie-break
  for (int off = 32; off; off >>= 1) {
    float ov = __shfl_down(best, off);
    int   oi = __shfl_down(bi, off);
    if (ov > best || (ov == best && oi < bi)) { best = ov; bi = oi; }
  }
  __shared__ float sv[4];
  __shared__ int   si[4];
  int wid = tid >> 6;
  if ((tid & 63) == 0) { sv[wid] = best; si[wid] = bi; }
  __syncthreads();
  if (tid == 0) {
#pragma unroll
    for (int w = 1; w < 4; ++w)
      if (sv[w] > best || (sv[w] == best && si[w] < bi)) { best = sv[w]; bi = si[w]; }
    ind_f[row]  = (float)bi;
    idx_ws[row] = bi;
    atomicAdd(&bins[bi], 1);
  }
}

// ---------------------------------------------------------------- K2b: exclusive prefix sum of bins -> cursor
__global__ __launch_bounds__(256) void k_scan(const int* __restrict__ bins,
                                              int* __restrict__ cursor) {
  const int tid  = threadIdx.x;
  const int lane = tid & 63;
  const int wid  = tid >> 6;
  int v[16];
  const int base = tid * 16;
  int run = 0;
#pragma unroll
  for (int i = 0; i < 16; ++i) { int t = bins[base + i]; v[i] = run; run += t; }
  // inclusive wave scan of per-thread totals
  int x = run;
  for (int d = 1; d < 64; d <<= 1) {
    int y = __shfl_up(x, d);
    if (lane >= d) x += y;
  }
  __shared__ int wtot[4];
  if (lane == 63) wtot[wid] = x;
  __syncthreads();
  int woff = 0;
  for (int w = 0; w < wid; ++w) woff += wtot[w];
  int ex = woff + x - run;                 // exclusive prefix for this thread's chunk
#pragma unroll
  for (int i = 0; i < 16; ++i) cursor[base + i] = ex + v[i];
}

// ---------------------------------------------------------------- K2c: scatter token ids into per-code lists
__global__ __launch_bounds__(256) void k_scatter_ids(const int* __restrict__ idx_ws,
                                                     int* __restrict__ cursor,
                                                     int* __restrict__ tlist) {
  int n = blockIdx.x * 256 + threadIdx.x;        // grid 128 -> 32768
  int c = idx_ws[n];
  int slot = atomicAdd(&cursor[c], 1);           // cursor ends at offset+count
  tlist[slot] = n;
}

// ---------------------------------------------------------------- K3: per-code gather: quantize + embed_sum + EMA
// One block per code c. Reads each X row exactly once; no float atomics.
__global__ __launch_bounds__(128) void k_embed_sum(const float* __restrict__ X,
                                                   const float* __restrict__ E,
                                                   const float* __restrict__ eavg,
                                                   const int* __restrict__ cursor, // end offsets
                                                   const int* __restrict__ bins,
                                                   const int* __restrict__ tlist,
                                                   float* __restrict__ quant,
                                                   float* __restrict__ avg) {
  const int c   = blockIdx.x;
  const int tid = threadIdx.x;                   // 128 threads x float4 = 512
  const int d4  = tid * 4;
  const int end = cursor[c];
  const int cnt = bins[c];
  const int start = end - cnt;
  float4 e = *(const float4*)(E + (size_t)c * DD + d4);
  float4 s = {0.f, 0.f, 0.f, 0.f};
  for (int t = start; t < end; ++t) {
    int n = tlist[t];
    float4 xv = *(const float4*)(X + (size_t)n * DD + d4);
    s.x += xv.x; s.y += xv.y; s.z += xv.z; s.w += xv.w;
    *(float4*)(quant + (size_t)n * DD + d4) = e;
  }
  float4 ea = *(const float4*)(eavg + (size_t)c * DD + d4);
  float4 o;
  o.x = DECAY_F * ea.x + OMD_F * s.x;
  o.y = DECAY_F * ea.y + OMD_F * s.y;
  o.z = DECAY_F * ea.z + OMD_F * s.z;
  o.w = DECAY_F * ea.w + OMD_F * s.w;
  *(float4*)(avg + (size_t)c * DD + d4) = o;
}

// ---------------------------------------------------------------- K4: new_cluster + total
__global__ __launch_bounds__(256) void k_cluster(const float* __restrict__ cs,
                                                 const int* __restrict__ bins,
                                                 float* __restrict__ nc_out,
                                                 float* __restrict__ tot) {
  int c = blockIdx.x * 256 + threadIdx.x;   // grid 16 -> 4096
  float nc = DECAY_F * cs[c] + OMD_F * (float)bins[c];
  nc_out[c] = nc;
  float s = nc;
  for (int off = 32; off; off >>= 1) s += __shfl_down(s, off);
  if ((threadIdx.x & 63) == 0) atomicAdd(tot, s);
}

// ---------------------------------------------------------------- K5: laplace-smooth + l2norm rows
__global__ __launch_bounds__(128) void k_norm(const float* __restrict__ avg,
                                              const float* __restrict__ nc,
                                              const float* __restrict__ tot,
                                              float* __restrict__ out) {
  int c = blockIdx.x;
  int tid = threadIdx.x;                     // 128 threads, D=512 -> float4 each
  const float* row = avg + (size_t)c * DD;
  float4 v = *(const float4*)(row + tid * 4);
  float ss = v.x * v.x + v.y * v.y + v.z * v.z + v.w * v.w;
  for (int off = 32; off; off >>= 1) ss += __shfl_down(ss, off);
  __shared__ float s2[2];
  if ((tid & 63) == 0) s2[tid >> 6] = ss;
  __syncthreads();
  float sumsq = s2[0] + s2[1];
  float t = *tot;
  float sm = (nc[c] + EPS_F) / (t + (float)CB * EPS_F) * t;   // > 0
  float nrm = sqrtf(sumsq) / sm;             // ||avg/sm||
  float denom = fmaxf(nrm, 1e-12f);
  float scale = 1.0f / (sm * denom);
  float4 o;
  o.x = v.x * scale; o.y = v.y * scale; o.z = v.z * scale; o.w = v.w * scale;
  *(float4*)(out + (size_t)c * DD + tid * 4) = o;
}

// ---------------------------------------------------------------- launch
extern "C" void kernel_launch(void* const* d_in, const int* in_sizes, int n_in,
                              void* d_out, int out_size, void* d_ws, size_t ws_size,
                              hipStream_t stream) {
  const float* x     = (const float*)d_in[0];   // (8,4096,512)
  const float* embed = (const float*)d_in[1];   // (1,4096,512)
  const float* cs    = (const float*)d_in[2];   // (1,4096)
  const float* eavg  = (const float*)d_in[3];   // (1,4096,512)

  float* out    = (float*)d_out;
  float* quant  = out + OFF_QUANT;
  float* indf   = out + OFF_IND;
  float* dist   = out + OFF_DIST;
  float* ncout  = out + OFF_NC;
  float* avgout = out + OFF_AVG;
  float* nemb   = out + OFF_NEMB;

  int*   idx_ws = (int*)d_ws;                 // 32768 ints
  int*   bins   = idx_ws + M_TOK;             // 4096 ints
  float* tot    = (float*)(bins + CB);        // 1 float

  // fp16 hi/lo scratch aliased onto not-yet-written output regions:
  //   X hi+lo (67.1 MB) -> quant region (written later by k_embed_sum)
  //   E hi+lo ( 8.4 MB) -> nemb region  (written last by k_norm)
  ushort_b* xhi = (ushort_b*)quant;
  ushort_b* xlo = xhi + (size_t)M_TOK * DD;
  ushort_b* ehi = (ushort_b*)nemb;
  ushort_b* elo = ehi + (size_t)CB * DD;

  // sort scratch aliased onto nemb region too (ehi/elo are dead after k_dist_mfma;
  // k_norm overwrites nemb only after k_embed_sum has consumed these)
  int* tlist  = (int*)nemb;                   // 32768 ints
  int* cursor = tlist + M_TOK;                // 4096 ints

  k_init<<<dim3(16), dim3(256), 0, stream>>>(bins, tot);
  k_split<<<dim3(M_TOK * DD / 8 / 256), dim3(256), 0, stream>>>(x, xhi, xlo);
  k_split<<<dim3(CB * DD / 8 / 256), dim3(256), 0, stream>>>(embed, ehi, elo);
  k_dist_mfma<<<dim3(CB / 128, M_TOK / 128), dim3(256), 0, stream>>>(xhi, xlo, ehi, elo, dist);
  k_argmax<<<dim3(M_TOK), dim3(256), 0, stream>>>(dist, indf, idx_ws, bins);
  k_scan<<<dim3(1), dim3(256), 0, stream>>>(bins, cursor);
  k_scatter_ids<<<dim3(M_TOK / 256), dim3(256), 0, stream>>>(idx_ws, cursor, tlist);
  k_embed_sum<<<dim3(CB), dim3(128), 0, stream>>>(x, embed, eavg, cursor, bins, tlist, quant, avgout);
  k_cluster<<<dim3(16), dim3(256), 0, stream>>>(cs, bins, ncout, tot);
  k_norm<<<dim3(CB), dim3(128), 0, stream>>>(avgout, ncout, tot, nemb);
}